// Round 1
// baseline (145.553 us; speedup 1.0000x reference)
//
#include <hip/hip_runtime.h>
#include <hip/hip_bf16.h>
#include <stdint.h>

typedef __bf16 bf16_t;
typedef bf16_t bf16x8 __attribute__((ext_vector_type(8)));
typedef bf16_t bf16x4 __attribute__((ext_vector_type(4)));
typedef float  f32x4  __attribute__((ext_vector_type(4)));

#define B_DIM 4096
#define I_DIM 1024
#define H_DIM 1024
#define K_DIM 2048   // I + H
#define N_DIM 4096   // 4*H

// ---------------------------------------------------------------------------
// Prep: A = [x | h_prev] cast to bf16, row-major [4096][2048]
// ---------------------------------------------------------------------------
__global__ void convA_kernel(const float* __restrict__ x,
                             const float* __restrict__ h,
                             bf16_t* __restrict__ A) {
    int idx = (blockIdx.x * 256 + threadIdx.x) * 4;   // element index into [B][2048]
    int b = idx >> 11;
    int c = idx & 2047;
    float4 v;
    if (c < I_DIM) v = *(const float4*)&x[(size_t)b * I_DIM + c];
    else           v = *(const float4*)&h[(size_t)b * H_DIM + (c - I_DIM)];
    bf16x4 o;
    o[0] = (bf16_t)v.x; o[1] = (bf16_t)v.y; o[2] = (bf16_t)v.z; o[3] = (bf16_t)v.w;
    *(bf16x4*)&A[idx] = o;
}

// ---------------------------------------------------------------------------
// Prep: Wcat row j (gate g = j>>10, r = j&1023) = [Wg[r,:] | Vg[r,:]] bf16
// ---------------------------------------------------------------------------
__global__ void convW_kernel(const float* __restrict__ W0, const float* __restrict__ W1,
                             const float* __restrict__ W2, const float* __restrict__ W3,
                             const float* __restrict__ V0, const float* __restrict__ V1,
                             const float* __restrict__ V2, const float* __restrict__ V3,
                             bf16_t* __restrict__ Wc) {
    int idx = (blockIdx.x * 256 + threadIdx.x) * 4;   // element index into [4096][2048]
    int j = idx >> 11;
    int c = idx & 2047;
    int g = j >> 10;
    int r = j & 1023;
    const float* src;
    if (c < I_DIM) {
        const float* Wg = (g == 0) ? W0 : (g == 1) ? W1 : (g == 2) ? W2 : W3;
        src = Wg + (size_t)r * I_DIM + c;
    } else {
        const float* Vg = (g == 0) ? V0 : (g == 1) ? V1 : (g == 2) ? V2 : V3;
        src = Vg + (size_t)r * H_DIM + (c - I_DIM);
    }
    float4 v = *(const float4*)src;
    bf16x4 o;
    o[0] = (bf16_t)v.x; o[1] = (bf16_t)v.y; o[2] = (bf16_t)v.z; o[3] = (bf16_t)v.w;
    *(bf16x4*)&Wc[idx] = o;
}

// ---------------------------------------------------------------------------
// Prep: bias_cat[j] = bW[g][r] + bV[g][r] + b[g][r]
// ---------------------------------------------------------------------------
__global__ void bias_kernel(const float* __restrict__ bW0, const float* __restrict__ bW1,
                            const float* __restrict__ bW2, const float* __restrict__ bW3,
                            const float* __restrict__ bV0, const float* __restrict__ bV1,
                            const float* __restrict__ bV2, const float* __restrict__ bV3,
                            const float* __restrict__ b0,  const float* __restrict__ b1,
                            const float* __restrict__ b2,  const float* __restrict__ b3,
                            float* __restrict__ bias) {
    int j = blockIdx.x * 256 + threadIdx.x;   // < 4096
    int g = j >> 10;
    int r = j & 1023;
    const float* bW = (g == 0) ? bW0 : (g == 1) ? bW1 : (g == 2) ? bW2 : bW3;
    const float* bV = (g == 0) ? bV0 : (g == 1) ? bV1 : (g == 2) ? bV2 : bV3;
    const float* bg = (g == 0) ? b0  : (g == 1) ? b1  : (g == 2) ? b2  : b3;
    bias[j] = bW[r] + bV[r] + bg[r];
}

// ---------------------------------------------------------------------------
// Prep: mask[b] = (||x_b||_2 > 0.001) ? 1 : 0
// ---------------------------------------------------------------------------
__global__ void mask_kernel(const float* __restrict__ x, float* __restrict__ mask) {
    int b = blockIdx.x;
    const float* row = x + (size_t)b * I_DIM;
    float s = 0.f;
    for (int i = threadIdx.x; i < I_DIM; i += 256) {
        float v = row[i];
        s += v * v;
    }
    #pragma unroll
    for (int off = 32; off > 0; off >>= 1) s += __shfl_down(s, off);
    __shared__ float ws[4];
    if ((threadIdx.x & 63) == 0) ws[threadIdx.x >> 6] = s;
    __syncthreads();
    if (threadIdx.x == 0) {
        float t = ws[0] + ws[1] + ws[2] + ws[3];
        mask[b] = (sqrtf(t) > 0.001f) ? 1.f : 0.f;
    }
}

// ---------------------------------------------------------------------------
// GEMM: gates[4096][4096] = A[4096][2048] * Wc[4096][2048]^T + bias
// m97 structure: 128x128 tile, BK=64, 4 waves (2x2 of 64x64), 16x16x32 MFMA,
// global_load_lds width-16 staging, 2 barriers per K-step.
// ---------------------------------------------------------------------------
#define TILE_M 128
#define TILE_N 128
#define TILE_K 64

__global__ __launch_bounds__(256, 2) void gemm_gates(
    const bf16_t* __restrict__ A,    // [4096][2048]
    const bf16_t* __restrict__ Wc,   // [4096][2048]
    const float* __restrict__ bias,  // [4096]
    float* __restrict__ gates)       // [4096][4096]
{
    __shared__ bf16_t lA[TILE_M * TILE_K];   // row-major [128][64]
    __shared__ bf16_t lB[TILE_N * TILE_K];   // row-major [128][64]

    const int tid  = threadIdx.x;
    const int lane = tid & 63;
    const int wave = tid >> 6;       // 0..3
    const int wm   = wave >> 1;      // 0..1  (M half)
    const int wn   = wave & 1;       // 0..1  (N half)

    const int m0 = blockIdx.y * TILE_M;
    const int n0 = blockIdx.x * TILE_N;

    f32x4 acc[4][4] = {};

    const int frow = lane & 15;           // row/col within 16x16 fragment
    const int kgrp = (lane >> 4) * 8;     // k offset within 32

    for (int k0 = 0; k0 < K_DIM; k0 += TILE_K) {
        // ---- stage A and B tiles (16 KiB each) via global_load_lds ----
        #pragma unroll
        for (int r = 0; r < 4; ++r) {
            int idx = r * 256 + tid;           // 0..1023
            int row = idx >> 3;                // 0..127
            int col = (idx & 7) * 8;           // 0,8,..,56
            const bf16_t* ga = A  + (size_t)(m0 + row) * K_DIM + k0 + col;
            const bf16_t* gb = Wc + (size_t)(n0 + row) * K_DIM + k0 + col;
            int ldsoff = (r * 256 + wave * 64) * 8;   // wave-uniform element offset
            __builtin_amdgcn_global_load_lds(
                (__attribute__((address_space(1))) void*)ga,
                (__attribute__((address_space(3))) void*)&lA[ldsoff], 16, 0, 0);
            __builtin_amdgcn_global_load_lds(
                (__attribute__((address_space(1))) void*)gb,
                (__attribute__((address_space(3))) void*)&lB[ldsoff], 16, 0, 0);
        }
        __syncthreads();

        // ---- consume tile: 2 k-halves x (4x4) MFMA ----
        #pragma unroll
        for (int kh = 0; kh < 2; ++kh) {
            bf16x8 af[4], bfr[4];
            #pragma unroll
            for (int t = 0; t < 4; ++t) {
                int arow = wm * 64 + t * 16 + frow;
                af[t]  = *(const bf16x8*)&lA[arow * TILE_K + kh * 32 + kgrp];
                int brow = wn * 64 + t * 16 + frow;
                bfr[t] = *(const bf16x8*)&lB[brow * TILE_K + kh * 32 + kgrp];
            }
            #pragma unroll
            for (int i = 0; i < 4; ++i)
                #pragma unroll
                for (int j = 0; j < 4; ++j)
                    acc[i][j] = __builtin_amdgcn_mfma_f32_16x16x32_bf16(
                        af[i], bfr[j], acc[i][j], 0, 0, 0);
        }
        __syncthreads();
    }

    // ---- epilogue: gates = acc + bias[col] ----
    const int crow = m0 + wm * 64;
    const int ccol = n0 + wn * 64;
    #pragma unroll
    for (int i = 0; i < 4; ++i) {
        #pragma unroll
        for (int j = 0; j < 4; ++j) {
            int col = ccol + j * 16 + (lane & 15);
            float bb = bias[col];
            #pragma unroll
            for (int r = 0; r < 4; ++r) {
                int row = crow + i * 16 + (lane >> 4) * 4 + r;
                gates[(size_t)row * N_DIM + col] = acc[i][j][r] + bb;
            }
        }
    }
}

// ---------------------------------------------------------------------------
// Epilogue: LSTM cell elementwise. Each block handles one batch row (1024 h).
// ---------------------------------------------------------------------------
__device__ __forceinline__ float sigmoidf_fast(float v) {
    return 1.f / (1.f + __expf(-v));
}
__device__ __forceinline__ float tanhf_fast(float v) {
    return 2.f / (1.f + __expf(-2.f * v)) - 1.f;
}

__global__ void lstm_epilogue(const float* __restrict__ gates,
                              const float* __restrict__ c_prev,
                              const float* __restrict__ mask,
                              float* __restrict__ out) {
    const int BH = B_DIM * H_DIM;
    int idx = blockIdx.x * 256 + threadIdx.x;   // thread handles 4 h-values
    int base = idx * 4;
    int b = base >> 10;
    int h = base & 1023;
    const size_t grow = (size_t)b * N_DIM;
    float4 fg = *(const float4*)&gates[grow + h];
    float4 ig = *(const float4*)&gates[grow + 1024 + h];
    float4 og = *(const float4*)&gates[grow + 2048 + h];
    float4 cg = *(const float4*)&gates[grow + 3072 + h];
    float4 cp = *(const float4*)&c_prev[base];
    float m = mask[b];

    float4 hn, cn, ct;
    {
        float f = sigmoidf_fast(fg.x), i = sigmoidf_fast(ig.x), o = sigmoidf_fast(og.x);
        ct.x = tanhf_fast(cg.x);
        cn.x = f * cp.x + i * cp.x + m * (i * ct.x);
        hn.x = o * tanhf_fast(cn.x);
    }
    {
        float f = sigmoidf_fast(fg.y), i = sigmoidf_fast(ig.y), o = sigmoidf_fast(og.y);
        ct.y = tanhf_fast(cg.y);
        cn.y = f * cp.y + i * cp.y + m * (i * ct.y);
        hn.y = o * tanhf_fast(cn.y);
    }
    {
        float f = sigmoidf_fast(fg.z), i = sigmoidf_fast(ig.z), o = sigmoidf_fast(og.z);
        ct.z = tanhf_fast(cg.z);
        cn.z = f * cp.z + i * cp.z + m * (i * ct.z);
        hn.z = o * tanhf_fast(cn.z);
    }
    {
        float f = sigmoidf_fast(fg.w), i = sigmoidf_fast(ig.w), o = sigmoidf_fast(og.w);
        ct.w = tanhf_fast(cg.w);
        cn.w = f * cp.w + i * cp.w + m * (i * ct.w);
        hn.w = o * tanhf_fast(cn.w);
    }
    *(float4*)&out[base]          = hn;
    *(float4*)&out[BH + base]     = cn;
    *(float4*)&out[2 * BH + base] = ct;
}

// ---------------------------------------------------------------------------
// Launch
// ---------------------------------------------------------------------------
extern "C" void kernel_launch(void* const* d_in, const int* in_sizes, int n_in,
                              void* d_out, int out_size, void* d_ws, size_t ws_size,
                              hipStream_t stream) {
    const float* x      = (const float*)d_in[0];
    const float* h_prev = (const float*)d_in[1];
    const float* c_prev = (const float*)d_in[2];
    // d_in[3] = c_prev_tilde_dummy (unused)
    const float* Wf = (const float*)d_in[4],  *bWf = (const float*)d_in[5];
    const float* Vf = (const float*)d_in[6],  *bVf = (const float*)d_in[7];
    const float* Wi = (const float*)d_in[8],  *bWi = (const float*)d_in[9];
    const float* Vi = (const float*)d_in[10], *bVi = (const float*)d_in[11];
    const float* Wo = (const float*)d_in[12], *bWo = (const float*)d_in[13];
    const float* Vo = (const float*)d_in[14], *bVo = (const float*)d_in[15];
    const float* Wcg = (const float*)d_in[16], *bWc = (const float*)d_in[17];
    const float* Vc = (const float*)d_in[18], *bVc = (const float*)d_in[19];
    const float* bf = (const float*)d_in[20];
    const float* bi = (const float*)d_in[21];
    const float* bo = (const float*)d_in[22];
    const float* bc = (const float*)d_in[23];

    uint8_t* ws = (uint8_t*)d_ws;
    bf16_t* Abuf  = (bf16_t*)ws;                                   // 16 MiB
    bf16_t* Wbuf  = (bf16_t*)(ws + (size_t)16 * 1024 * 1024);      // 16 MiB
    float*  gates = (float*)(ws + (size_t)32 * 1024 * 1024);       // 64 MiB
    float*  biasb = (float*)(ws + (size_t)96 * 1024 * 1024);       // 16 KiB
    float*  maskb = biasb + 4096;                                  // 16 KiB

    // Prep
    convA_kernel<<<(B_DIM * K_DIM / 4) / 256, 256, 0, stream>>>(x, h_prev, Abuf);
    convW_kernel<<<(N_DIM * K_DIM / 4) / 256, 256, 0, stream>>>(
        Wf, Wi, Wo, Wcg, Vf, Vi, Vo, Vc, Wbuf);
    bias_kernel<<<N_DIM / 256, 256, 0, stream>>>(
        bWf, bWi, bWo, bWc, bVf, bVi, bVo, bVc, bf, bi, bo, bc, biasb);
    mask_kernel<<<B_DIM, 256, 0, stream>>>(x, maskb);

    // GEMM
    dim3 ggrid(N_DIM / TILE_N, B_DIM / TILE_M);
    gemm_gates<<<ggrid, 256, 0, stream>>>(Abuf, Wbuf, biasb, gates);

    // Epilogue
    lstm_epilogue<<<(B_DIM * H_DIM / 4) / 256, 256, 0, stream>>>(
        gates, c_prev, maskb, (float*)d_out);
}

// Round 2
// 101.321 us; speedup vs baseline: 1.4366x; 1.4366x over previous
//
#include <hip/hip_runtime.h>
#include <hip/hip_bf16.h>
#include <stdint.h>

typedef __bf16 bf16_t;
typedef bf16_t bf16x8 __attribute__((ext_vector_type(8)));
typedef bf16_t bf16x4 __attribute__((ext_vector_type(4)));
typedef float  f32x4  __attribute__((ext_vector_type(4)));

#define B_DIM 4096
#define I_DIM 1024
#define H_DIM 1024
#define K_DIM 2048   // I + H
#define N_DIM 4096   // 4*H
#define NT    (K_DIM / 64)   // 32 K-tiles

// ---------------------------------------------------------------------------
// Prep: A = [x | h_prev] cast to bf16, row-major [4096][2048]
// ---------------------------------------------------------------------------
__global__ void convA_kernel(const float* __restrict__ x,
                             const float* __restrict__ h,
                             bf16_t* __restrict__ A) {
    int idx = (blockIdx.x * 256 + threadIdx.x) * 4;
    int b = idx >> 11;
    int c = idx & 2047;
    float4 v;
    if (c < I_DIM) v = *(const float4*)&x[(size_t)b * I_DIM + c];
    else           v = *(const float4*)&h[(size_t)b * H_DIM + (c - I_DIM)];
    bf16x4 o;
    o[0] = (bf16_t)v.x; o[1] = (bf16_t)v.y; o[2] = (bf16_t)v.z; o[3] = (bf16_t)v.w;
    *(bf16x4*)&A[idx] = o;
}

// ---------------------------------------------------------------------------
// Prep: Wcat in GATE-INTERLEAVED column order.
// Output row n (a gates-column): g = (n>>4)&3, h = (n>>6)*16 + (n&15).
// Row data = [Wg[h, 0:1024] | Vg[h, 0:1024]] in bf16.
// ---------------------------------------------------------------------------
__global__ void convW_kernel(const float* __restrict__ W0, const float* __restrict__ W1,
                             const float* __restrict__ W2, const float* __restrict__ W3,
                             const float* __restrict__ V0, const float* __restrict__ V1,
                             const float* __restrict__ V2, const float* __restrict__ V3,
                             bf16_t* __restrict__ Wc) {
    int idx = (blockIdx.x * 256 + threadIdx.x) * 4;   // element in [4096][2048]
    int n = idx >> 11;
    int c = idx & 2047;
    int g = (n >> 4) & 3;
    int h = ((n >> 6) << 4) + (n & 15);
    const float* src;
    if (c < I_DIM) {
        const float* Wg = (g == 0) ? W0 : (g == 1) ? W1 : (g == 2) ? W2 : W3;
        src = Wg + (size_t)h * I_DIM + c;
    } else {
        const float* Vg = (g == 0) ? V0 : (g == 1) ? V1 : (g == 2) ? V2 : V3;
        src = Vg + (size_t)h * H_DIM + (c - I_DIM);
    }
    float4 v = *(const float4*)src;
    bf16x4 o;
    o[0] = (bf16_t)v.x; o[1] = (bf16_t)v.y; o[2] = (bf16_t)v.z; o[3] = (bf16_t)v.w;
    *(bf16x4*)&Wc[idx] = o;
}

// ---------------------------------------------------------------------------
// Prep: bias in the same interleaved order
// ---------------------------------------------------------------------------
__global__ void bias_kernel(const float* __restrict__ bW0, const float* __restrict__ bW1,
                            const float* __restrict__ bW2, const float* __restrict__ bW3,
                            const float* __restrict__ bV0, const float* __restrict__ bV1,
                            const float* __restrict__ bV2, const float* __restrict__ bV3,
                            const float* __restrict__ b0,  const float* __restrict__ b1,
                            const float* __restrict__ b2,  const float* __restrict__ b3,
                            float* __restrict__ bias) {
    int n = blockIdx.x * 256 + threadIdx.x;   // < 4096
    int g = (n >> 4) & 3;
    int h = ((n >> 6) << 4) + (n & 15);
    const float* bW = (g == 0) ? bW0 : (g == 1) ? bW1 : (g == 2) ? bW2 : bW3;
    const float* bV = (g == 0) ? bV0 : (g == 1) ? bV1 : (g == 2) ? bV2 : bV3;
    const float* bg = (g == 0) ? b0  : (g == 1) ? b1  : (g == 2) ? b2  : b3;
    bias[n] = bW[h] + bV[h] + bg[h];
}

// ---------------------------------------------------------------------------
// Prep: mask[b] = (||x_b||_2 > 0.001) ? 1 : 0
// ---------------------------------------------------------------------------
__global__ void mask_kernel(const float* __restrict__ x, float* __restrict__ mask) {
    int b = blockIdx.x;
    const float* row = x + (size_t)b * I_DIM;
    float s = 0.f;
    for (int i = threadIdx.x; i < I_DIM; i += 256) {
        float v = row[i];
        s += v * v;
    }
    #pragma unroll
    for (int off = 32; off > 0; off >>= 1) s += __shfl_down(s, off);
    __shared__ float ws[4];
    if ((threadIdx.x & 63) == 0) ws[threadIdx.x >> 6] = s;
    __syncthreads();
    if (threadIdx.x == 0) {
        float t = ws[0] + ws[1] + ws[2] + ws[3];
        mask[b] = (sqrtf(t) > 0.001f) ? 1.f : 0.f;
    }
}

// ---------------------------------------------------------------------------
// Fused GEMM + LSTM cell.
// gates = A[4096][2048] * Wc[4096][2048]^T (+bias), then LSTM elementwise.
// 256x256 tile, BK=64, 8 waves (2M x 4N), double-buffered LDS (128 KiB),
// 4 phases per K-tile with counted vmcnt(4), raw s_barrier, setprio on MFMA.
// LDS layout per matrix: [kh 2][row 256][col 32] bf16 (16 KB planes), XOR swz.
// ---------------------------------------------------------------------------
__device__ __forceinline__ int swz(int byte) {
    return byte ^ (((byte >> 7) & 3) << 4);
}
__device__ __forceinline__ float sigf(float v) { return 1.f / (1.f + __expf(-v)); }
__device__ __forceinline__ float tanf_(float v) { return 2.f / (1.f + __expf(-2.f * v)) - 1.f; }

#define BARRIER()  asm volatile("s_barrier" ::: "memory")
#define WAIT_VM4() asm volatile("s_waitcnt vmcnt(4)" ::: "memory")

__global__ __launch_bounds__(512, 2) void gemm_lstm(
    const bf16_t* __restrict__ A,     // [4096][2048]
    const bf16_t* __restrict__ W,     // [4096][2048] gate-interleaved rows
    const float* __restrict__ bias,   // [4096] interleaved
    const float* __restrict__ c_prev, // [4096][1024]
    const float* __restrict__ mask,   // [4096]
    float* __restrict__ out)          // [3][4096][1024]
{
    __shared__ bf16_t smem[65536];    // 128 KiB: [buf2][mat2][kh2][256][32]

    const int tid  = threadIdx.x;
    const int lane = tid & 63;
    const int wave = tid >> 6;     // 0..7
    const int wm   = wave >> 2;    // 0..1
    const int wn   = wave & 3;     // 0..3
    const int frow = lane & 15;
    const int g    = lane >> 4;    // 0..3 (k-group)

    // XCD-aware block swizzle (grid = 256, divisible by 8)
    int bid = blockIdx.x;
    int wg  = (bid & 7) * 32 + (bid >> 3);
    const int m0 = (wg >> 4) * 256;
    const int n0 = (wg & 15) * 256;

    // Precomputed swizzled read offsets (elements) within one [256][32] plane
    int aoffE[8], boffE[4];
    #pragma unroll
    for (int mi = 0; mi < 8; ++mi) {
        int row = wm * 128 + mi * 16 + frow;
        aoffE[mi] = swz(row * 64 + g * 16) >> 1;
    }
    #pragma unroll
    for (int nj = 0; nj < 4; ++nj) {
        int row = wn * 64 + nj * 16 + frow;
        boffE[nj] = swz(row * 64 + g * 16) >> 1;
    }

    // Stage one 16 KB half-tile (mat, kh) of K-tile kt into buffer nb.
    // LDS dest is linear (wave-uniform base + lane*16); swizzle applied to
    // the GLOBAL source address (inverse == same, XOR involution).
    auto stage = [&](int nb, int mat, int kh, int kt) {
        const bf16_t* base = (mat == 0) ? A : W;
        const int R0 = (mat == 0) ? m0 : n0;
        const int kk = kt * 64 + kh * 32;
        #pragma unroll
        for (int p = 0; p < 2; ++p) {
            int d = (p * 512 + tid) * 16;       // byte in 16 KB plane (linear)
            int l = swz(d);                     // logical byte
            int row = l >> 6;
            int ce  = (l & 63) >> 1;
            const bf16_t* src = base + (size_t)(R0 + row) * K_DIM + kk + ce;
            int dstE = nb * 32768 + mat * 16384 + kh * 8192 + (p * 512 + wave * 64) * 8;
            __builtin_amdgcn_global_load_lds(
                (__attribute__((address_space(1))) void*)src,
                (__attribute__((address_space(3))) void*)&smem[dstE], 16, 0, 0);
        }
    };

    f32x4 acc[8][4] = {};

    // Prologue: stage K-tile 0 into buf 0 (order: Akh0, Bkh0, Akh1, Bkh1)
    stage(0, 0, 0, 0);
    stage(0, 1, 0, 0);
    stage(0, 0, 1, 0);
    stage(0, 1, 1, 0);
    WAIT_VM4();       // Akh0, Bkh0 landed; Akh1, Bkh1 still in flight
    BARRIER();

    bf16x8 bfrag[4];

    for (int t = 0; t < NT; ++t) {
        const int buf = t & 1, nb = buf ^ 1;
        const int nt  = (t + 1 < NT) ? t + 1 : 0;   // wrap: keeps vmcnt uniform
        const bf16_t* sA = &smem[buf * 32768];
        const bf16_t* sB = &smem[buf * 32768 + 16384];

        #pragma unroll
        for (int kh = 0; kh < 2; ++kh) {
            #pragma unroll
            for (int mh = 0; mh < 2; ++mh) {
                // --- ds-load register subtile ---
                if (mh == 0) {
                    #pragma unroll
                    for (int nj = 0; nj < 4; ++nj)
                        bfrag[nj] = *(const bf16x8*)&sB[kh * 8192 + boffE[nj]];
                }
                bf16x8 af[4];
                #pragma unroll
                for (int mi = 0; mi < 4; ++mi)
                    af[mi] = *(const bf16x8*)&sA[kh * 8192 + aoffE[mh * 4 + mi]];

                // --- stage one half-tile of next K-tile ---
                stage(nb, mh, kh, nt);   // P0:Akh0 P1:Bkh0 P2:Akh1 P3:Bkh1

                BARRIER();
                __builtin_amdgcn_s_setprio(1);
                #pragma unroll
                for (int mi = 0; mi < 4; ++mi)
                    #pragma unroll
                    for (int nj = 0; nj < 4; ++nj)
                        acc[mh * 4 + mi][nj] = __builtin_amdgcn_mfma_f32_16x16x32_bf16(
                            af[mi], bfrag[nj], acc[mh * 4 + mi][nj], 0, 0, 0);
                __builtin_amdgcn_s_setprio(0);
                if (mh == 1) WAIT_VM4();   // guard next (kh/tile) phase's reads
                BARRIER();
            }
        }
    }

    // ----- fused LSTM epilogue (in-register: lane's 4 n-frags = 4 gates) -----
    const int ncol = n0 + wn * 64;
    float bv[4];
    #pragma unroll
    for (int j = 0; j < 4; ++j) bv[j] = bias[ncol + j * 16 + frow];
    const int hb = (n0 >> 2) + wn * 16 + frow;   // h index for this lane
    const int BH = B_DIM * H_DIM;

    #pragma unroll
    for (int mi = 0; mi < 8; ++mi) {
        int bbase = m0 + wm * 128 + mi * 16 + g * 4;
        #pragma unroll
        for (int r = 0; r < 4; ++r) {
            int b = bbase + r;
            float mk = mask[b];
            float cp = c_prev[(size_t)b * H_DIM + hb];
            float fv = sigf(acc[mi][0][r] + bv[0]);
            float iv = sigf(acc[mi][1][r] + bv[1]);
            float ov = sigf(acc[mi][2][r] + bv[2]);
            float ct = tanf_(acc[mi][3][r] + bv[3]);
            float cn = fv * cp + iv * cp + mk * (iv * ct);
            float hn = ov * tanf_(cn);
            size_t o = (size_t)b * H_DIM + hb;
            out[o]          = hn;
            out[BH + o]     = cn;
            out[2 * BH + o] = ct;
        }
    }
}

// ---------------------------------------------------------------------------
// Launch
// ---------------------------------------------------------------------------
extern "C" void kernel_launch(void* const* d_in, const int* in_sizes, int n_in,
                              void* d_out, int out_size, void* d_ws, size_t ws_size,
                              hipStream_t stream) {
    const float* x      = (const float*)d_in[0];
    const float* h_prev = (const float*)d_in[1];
    const float* c_prev = (const float*)d_in[2];
    const float* Wf = (const float*)d_in[4],  *bWf = (const float*)d_in[5];
    const float* Vf = (const float*)d_in[6],  *bVf = (const float*)d_in[7];
    const float* Wi = (const float*)d_in[8],  *bWi = (const float*)d_in[9];
    const float* Vi = (const float*)d_in[10], *bVi = (const float*)d_in[11];
    const float* Wo = (const float*)d_in[12], *bWo = (const float*)d_in[13];
    const float* Vo = (const float*)d_in[14], *bVo = (const float*)d_in[15];
    const float* Wcg = (const float*)d_in[16], *bWc = (const float*)d_in[17];
    const float* Vc = (const float*)d_in[18], *bVc = (const float*)d_in[19];
    const float* bf = (const float*)d_in[20];
    const float* bi = (const float*)d_in[21];
    const float* bo = (const float*)d_in[22];
    const float* bc = (const float*)d_in[23];

    uint8_t* ws = (uint8_t*)d_ws;
    bf16_t* Abuf  = (bf16_t*)ws;                                   // 16 MiB
    bf16_t* Wbuf  = (bf16_t*)(ws + (size_t)16 * 1024 * 1024);      // 16 MiB
    float*  biasb = (float*)(ws + (size_t)32 * 1024 * 1024);       // 16 KiB
    float*  maskb = biasb + 4096;                                  // 16 KiB

    convA_kernel<<<(B_DIM * K_DIM / 4) / 256, 256, 0, stream>>>(x, h_prev, Abuf);
    convW_kernel<<<(N_DIM * K_DIM / 4) / 256, 256, 0, stream>>>(
        Wf, Wi, Wo, Wcg, Vf, Vi, Vo, Vc, Wbuf);
    bias_kernel<<<N_DIM / 256, 256, 0, stream>>>(
        bWf, bWi, bWo, bWc, bVf, bVi, bVo, bVc, bf, bi, bo, bc, biasb);
    mask_kernel<<<B_DIM, 256, 0, stream>>>(x, maskb);

    gemm_lstm<<<256, 512, 0, stream>>>(Abuf, Wbuf, biasb, c_prev, maskb,
                                       (float*)d_out);
}